// Round 1
// baseline (118.704 us; speedup 1.0000x reference)
//
#include <hip/hip_runtime.h>

// AdderNet 2D: out[n,f,i,j] = -sum_{c,ki,kj} |W[f,c,ki,kj] - xpad[n,c,i+ki,j+kj]|
// x: [8,64,32,32] f32, W: [64,64,3,3] f32, out: [8,64,32,32] f32
//
// Block: one n, a 32-wide x 8-tall output tile, 4 filters. 512 blocks (2/CU).
// x tile (+1 halo) staged in LDS in channel chunks; W read via wave-uniform
// (scalar) loads; per-thread register blocking: 1 pixel x 4 filters, with the
// 3 LDS x-values reused across kj and all 4 filters.

#define TILE_H 8
#define TILE_W 32
#define HALO_H (TILE_H + 2)    // 10
#define HALO_W (TILE_W + 2)    // 34
#define HALO_SZ (HALO_H * HALO_W)  // 340
#define CCHUNK 32
#define FPB 4                  // filters per block

__global__ __launch_bounds__(256, 2)
void adder2d_kernel(const float* __restrict__ x,
                    const float* __restrict__ Wt,
                    float* __restrict__ out) {
    __shared__ float xs[CCHUNK * HALO_SZ];   // 32*340*4 = 43520 B

    const int bid  = blockIdx.x;
    const int fg   = bid & 15;        // filter group fastest -> x-tile L2/L3 reuse
    const int tile = (bid >> 4) & 3;  // row tile
    const int n    = bid >> 6;        // image
    const int f0   = fg * FPB;
    const int i0   = tile * TILE_H;

    const int tid = threadIdx.x;
    const int r   = tid >> 5;         // 0..7  output row within tile
    const int j   = tid & 31;         // 0..31 output col

    float acc[FPB];
#pragma unroll
    for (int ff = 0; ff < FPB; ++ff) acc[ff] = 0.0f;

    const float* xn = x + (size_t)n * 64 * 1024;

    for (int c0 = 0; c0 < 64; c0 += CCHUNK) {
        // ---- stage x chunk into LDS (zero-padded halo) ----
        for (int cc = 0; cc < CCHUNK; ++cc) {
            const float* xc = xn + (size_t)(c0 + cc) * 1024;
            for (int idx = tid; idx < HALO_SZ; idx += 256) {
                const int h  = idx / HALO_W;
                const int hc = idx - h * HALO_W;
                const int ir = i0 + h - 1;
                const int ic = hc - 1;
                float v = 0.0f;
                if ((unsigned)ir < 32u && (unsigned)ic < 32u)
                    v = xc[ir * 32 + ic];
                xs[cc * HALO_SZ + idx] = v;
            }
        }
        __syncthreads();

        // ---- compute ----
#pragma unroll 4
        for (int cc = 0; cc < CCHUNK; ++cc) {
            const int c = c0 + cc;
            const float* wbase = Wt + (size_t)c * 9;   // + f*576 below
#pragma unroll
            for (int ki = 0; ki < 3; ++ki) {
                const int xoff = cc * HALO_SZ + (r + ki) * HALO_W + j;
                const float xv0 = xs[xoff + 0];
                const float xv1 = xs[xoff + 1];
                const float xv2 = xs[xoff + 2];
#pragma unroll
                for (int ff = 0; ff < FPB; ++ff) {
                    // W index is wave-uniform -> scalar loads (SGPR broadcast)
                    const float* w = wbase + (size_t)(f0 + ff) * 576 + ki * 3;
                    acc[ff] += fabsf(w[0] - xv0) + fabsf(w[1] - xv1)
                             + fabsf(w[2] - xv2);
                }
            }
        }
        __syncthreads();
    }

    const int irow = i0 + r;
#pragma unroll
    for (int ff = 0; ff < FPB; ++ff) {
        out[(((size_t)n * 64 + (f0 + ff)) * 32 + irow) * 32 + j] = -acc[ff];
    }
}

extern "C" void kernel_launch(void* const* d_in, const int* in_sizes, int n_in,
                              void* d_out, int out_size, void* d_ws, size_t ws_size,
                              hipStream_t stream) {
    const float* x  = (const float*)d_in[0];
    const float* W  = (const float*)d_in[1];
    float* out      = (float*)d_out;
    hipLaunchKernelGGL(adder2d_kernel, dim3(512), dim3(256), 0, stream,
                       x, W, out);
}

// Round 2
// 92.951 us; speedup vs baseline: 1.2771x; 1.2771x over previous
//
#include <hip/hip_runtime.h>

// AdderNet 2D: out[n,f,i,j] = -sum_{c,ki,kj} |W[f,c,ki,kj] - xpad[n,c,i+ki,j+kj]|
// x: [8,64,32,32] f32, W: [64,64,3,3] f32, out: [8,64,32,32] f32
//
// R2: split-K=4 over channels (2048 blocks, 6 blocks/CU by LDS), W staged in
// LDS (kills s_load/lgkmcnt(0) serialization of the hot loop), single staging
// barrier, fp32 atomicAdd combine onto memset-zeroed output.

#define TILE_H 8
#define TILE_W 32
#define CCHUNK 16          // channels per block (64 / split-K)
#define FPB    4           // filters per block
#define XROW   36          // padded halo row: col -1 -> 0, 0..31 -> 1..32, 32 -> 33
#define HALO_H (TILE_H + 2)       // 10
#define XCH    (HALO_H * XROW)    // 360 floats per channel
#define WPAD   12          // 9 weights padded to 12 -> 16B-aligned float4 reads

__global__ __launch_bounds__(256, 6)
void adder2d_kernel(const float* __restrict__ x,
                    const float* __restrict__ Wt,
                    float* __restrict__ out) {
    __shared__ float xs[CCHUNK * XCH];          // 16*360*4 = 23040 B
    __shared__ float ws[FPB * CCHUNK * WPAD];   // 4*16*12*4 =  3072 B

    const int bid  = blockIdx.x;
    const int ks   = bid & 3;          // channel-split slice
    const int fg   = (bid >> 2) & 15;  // filter group
    const int tile = (bid >> 6) & 3;   // row tile
    const int n    = bid >> 8;         // image
    const int c0   = ks * CCHUNK;
    const int f0   = fg * FPB;
    const int i0   = tile * TILE_H;
    const int tid  = threadIdx.x;

    // ---- stage W chunk: [FPB][CCHUNK][9] -> ws[f][cc][0..8] (pad 9..11 unread)
    for (int idx = tid; idx < FPB * CCHUNK * 9; idx += 256) {
        const int f   = idx / (CCHUNK * 9);
        const int rem = idx - f * (CCHUNK * 9);
        const int cc  = rem / 9;
        const int kk  = rem - cc * 9;
        ws[(f * CCHUNK + cc) * WPAD + kk] =
            Wt[((size_t)(f0 + f) * 64 + (c0 + cc)) * 9 + kk];
    }

    // ---- stage x chunk with zero-padded halo
    const float* xn = x + ((size_t)n * 64 + c0) * 1024;
    for (int idx = tid; idx < CCHUNK * XCH; idx += 256) {
        const int cc  = idx / XCH;
        const int rem = idx - cc * XCH;
        const int row = rem / XROW;
        const int col = rem - row * XROW;
        const int ir  = i0 + row - 1;
        const int ic  = col - 1;
        float v = 0.0f;
        if ((unsigned)ir < 32u && (unsigned)ic < 32u)
            v = xn[cc * 1024 + ir * 32 + ic];
        xs[idx] = v;
    }
    __syncthreads();

    const int r = tid >> 5;   // output row in tile
    const int j = tid & 31;   // output col

    float acc[FPB];
#pragma unroll
    for (int f = 0; f < FPB; ++f) acc[f] = 0.0f;

#pragma unroll 2
    for (int cc = 0; cc < CCHUNK; ++cc) {
        const float* xp = &xs[cc * XCH + r * XROW + j];
        const float x00 = xp[0],  x01 = xp[1],  x02 = xp[2];
        const float x10 = xp[36], x11 = xp[37], x12 = xp[38];
        const float x20 = xp[72], x21 = xp[73], x22 = xp[74];
        const float* wp = &ws[cc * WPAD];
#pragma unroll
        for (int f = 0; f < FPB; ++f) {
            const float4 wa = *(const float4*)&wp[f * CCHUNK * WPAD];
            const float4 wb = *(const float4*)&wp[f * CCHUNK * WPAD + 4];
            const float  w8 = wp[f * CCHUNK * WPAD + 8];
            acc[f] += fabsf(wa.x - x00) + fabsf(wa.y - x01) + fabsf(wa.z - x02)
                    + fabsf(wa.w - x10) + fabsf(wb.x - x11) + fabsf(wb.y - x12)
                    + fabsf(wb.z - x20) + fabsf(wb.w - x21) + fabsf(w8  - x22);
        }
    }

    const int irow = i0 + r;
#pragma unroll
    for (int f = 0; f < FPB; ++f) {
        atomicAdd(&out[(((size_t)n * 64 + (f0 + f)) * 32 + irow) * 32 + j],
                  -acc[f]);
    }
}

extern "C" void kernel_launch(void* const* d_in, const int* in_sizes, int n_in,
                              void* d_out, int out_size, void* d_ws, size_t ws_size,
                              hipStream_t stream) {
    const float* x  = (const float*)d_in[0];
    const float* W  = (const float*)d_in[1];
    float* out      = (float*)d_out;
    hipMemsetAsync(d_out, 0, (size_t)out_size * sizeof(float), stream);
    hipLaunchKernelGGL(adder2d_kernel, dim3(2048), dim3(256), 0, stream,
                       x, W, out);
}